// Round 5
// baseline (283.056 us; speedup 1.0000x reference)
//
#include <hip/hip_runtime.h>

// Problem: out[b] = weight[layer_ids[b]] @ z[b] + bias[layer_ids[b]]
// All fp32 (layer_ids int32). z[4096,1024], weight[16,1024,1024],
// bias[16,1024], out[4096,1024].
// R5 (bisection): counting-sort + grouped fp32 VALU SGEMM, NO MFMA.
// Exact fp32 math isolates the sort/gather/epilogue scaffold from the
// MFMA fragment-layout hypothesis space.

#define HDIM 1024
#define LNUM 16
#define BTOT 4096

constexpr int BM = 64, BN = 64, BK = 16;
constexpr int LDT = 68;  // padded LDS leading dim: 16B-aligned rows, spread banks

typedef __attribute__((ext_vector_type(4))) float floatx4;

// ---------------------------------------------------------------------------
// Kernel 1: group batch rows by layer (counting sort). Single block.
// ---------------------------------------------------------------------------
__global__ void group_kernel(const int* __restrict__ layer_ids,
                             int* __restrict__ perm,
                             int* __restrict__ offsets) {
    __shared__ int cnt[LNUM];
    __shared__ int base[LNUM];
    const int t = threadIdx.x;
    if (t < LNUM) cnt[t] = 0;
    __syncthreads();
    for (int b = t; b < BTOT; b += 256)
        atomicAdd(&cnt[layer_ids[b] & (LNUM - 1)], 1);
    __syncthreads();
    if (t == 0) {
        int acc = 0;
        for (int l = 0; l < LNUM; ++l) {
            base[l] = acc;
            offsets[l] = acc;
            acc += cnt[l];
        }
        offsets[LNUM] = acc;
    }
    __syncthreads();
    if (t < LNUM) cnt[t] = 0;
    __syncthreads();
    for (int b = t; b < BTOT; b += 256) {
        int l = layer_ids[b] & (LNUM - 1);
        int p = base[l] + atomicAdd(&cnt[l], 1);
        perm[p] = b;
    }
}

// ---------------------------------------------------------------------------
// Kernel 2: grouped fp32 SGEMM. 256 threads, 64x64 tile, BK=16.
// Thread (tm=tid&15, tn=tid>>4) computes a 4x4 micro-tile.
// As[k][m] = z[perm[off+m0+m]][k0+k]; Bs[k][n] = weight[l][n0+n][k0+k].
// out[perm[off+m]][n] = sum_k As*Bs + bias[l][n].
// ---------------------------------------------------------------------------
__global__ __launch_bounds__(256) void grouped_sgemm_kernel(
    const float* __restrict__ z,
    const float* __restrict__ weight,
    const float* __restrict__ bias,
    const int* __restrict__ perm,
    const int* __restrict__ offsets,
    float* __restrict__ out) {

    const int l = blockIdx.z;
    const int off = offsets[l];
    const int cnt = offsets[l + 1] - off;
    const int m0 = blockIdx.y * BM;
    if (m0 >= cnt) return;  // dead tile, uniform exit
    const int n0 = blockIdx.x * BN;

    __shared__ float As[BK][LDT];
    __shared__ float Bs[BK][LDT];

    const int tid = threadIdx.x;
    const int tm = tid & 15;   // micro-tile m group
    const int tn = tid >> 4;   // micro-tile n group

    // Staging map: sid = tid + p*256 over 16(k) x 64(row): k=sid&15, row=sid>>4.
    const int sk = tid & 15;
    const int sr0 = tid >> 4;  // row base; +16 per p

    const float* aRow[4];
#pragma unroll
    for (int p = 0; p < 4; ++p) {
        int gm = m0 + sr0 + p * 16;
        if (gm > cnt - 1) gm = cnt - 1;  // clamp (stores guarded)
        aRow[p] = z + (size_t)perm[off + gm] * HDIM;
    }
    const float* wBase = weight + (size_t)l * HDIM * HDIM;

    float acc[4][4] = {};  // [i=m][j=n]

    for (int k0 = 0; k0 < HDIM; k0 += BK) {
        // Global -> VGPR (before barrier; overlaps prior compute)
        float av[4], bv[4];
#pragma unroll
        for (int p = 0; p < 4; ++p) {
            av[p] = aRow[p][k0 + sk];
            bv[p] = wBase[(size_t)(n0 + sr0 + p * 16) * HDIM + k0 + sk];
        }
        __syncthreads();  // prior iteration's LDS reads done
#pragma unroll
        for (int p = 0; p < 4; ++p) {
            As[sk][sr0 + p * 16] = av[p];
            Bs[sk][sr0 + p * 16] = bv[p];
        }
        __syncthreads();  // staging visible

#pragma unroll
        for (int k = 0; k < BK; ++k) {
            floatx4 a = *(const floatx4*)&As[k][tm * 4];
            floatx4 b = *(const floatx4*)&Bs[k][tn * 4];
#pragma unroll
            for (int i = 0; i < 4; ++i)
#pragma unroll
                for (int j = 0; j < 4; ++j)
                    acc[i][j] = fmaf(a[i], b[j], acc[i][j]);
        }
    }

    // Epilogue: float4 store of 4 consecutive n per m-row, + bias.
    const int nbase = n0 + tn * 4;
    floatx4 bb = *(const floatx4*)&bias[l * HDIM + nbase];
#pragma unroll
    for (int i = 0; i < 4; ++i) {
        int gm = m0 + tm * 4 + i;
        if (gm < cnt) {
            int bidx = perm[off + gm];
            floatx4 v;
#pragma unroll
            for (int j = 0; j < 4; ++j) v[j] = acc[i][j] + bb[j];
            *(floatx4*)&out[(size_t)bidx * HDIM + nbase] = v;
        }
    }
}

extern "C" void kernel_launch(void* const* d_in, const int* in_sizes, int n_in,
                              void* d_out, int out_size, void* d_ws, size_t ws_size,
                              hipStream_t stream) {
    // Order-proof pointer resolution (validated in R4: dict order, sizes match).
    const float* z = nullptr;
    const int* layer_ids = nullptr;
    const float* weight = nullptr;
    const float* bias = nullptr;
    for (int i = 0; i < n_in; ++i) {
        switch (in_sizes[i]) {
            case BTOT * HDIM:        z = (const float*)d_in[i]; break;
            case BTOT:               layer_ids = (const int*)d_in[i]; break;
            case LNUM * HDIM * HDIM: weight = (const float*)d_in[i]; break;
            case LNUM * HDIM:        bias = (const float*)d_in[i]; break;
        }
    }
    float* out = (float*)d_out;

    int* perm = (int*)d_ws;       // 4096 ints
    int* offsets = perm + BTOT;   // 17 ints

    group_kernel<<<1, 256, 0, stream>>>(layer_ids, perm, offsets);

    // x = 16 n-tiles, y = m-slots (covers cnt<=2048; binomial max ~310), z = layer.
    dim3 grid(HDIM / BN, 32, LNUM);
    grouped_sgemm_kernel<<<grid, 256, 0, stream>>>(z, weight, bias, perm,
                                                   offsets, out);
}